// Round 5
// baseline (574.827 us; speedup 1.0000x reference)
//
#include <hip/hip_runtime.h>
#include <hip/hip_bf16.h>
#include <cstdint>
#include <cstddef>

// Problem constants (fixed by the reference)
#define TDIM 1024
#define HDIM 1024
#define FDIM 2048
#define NEXP 8
#define NENT 2048   // T * K

typedef __bf16 bf16_t;
typedef __bf16 bf16x4 __attribute__((ext_vector_type(4)));
typedef __bf16 bf16x8 __attribute__((ext_vector_type(8)));
typedef float  f32x4  __attribute__((ext_vector_type(4)));

#define H_ELEMS ((size_t)TDIM*HDIM)   // 1048576

// ---------------- workspace layout (bytes) ----------------
#define WB_OFFSETS 0                                   // int[16]
#define WB_ETOK    64
#define WB_ESCALE  (WB_ETOK + NENT*4)
#define WB_ACT     16512                               // bf16[NENT][FDIM] = 8 MB
#define WB_H       (WB_ACT + (size_t)NENT*FDIM*2)      // bf16[T][H] = 2 MB

// ---------------- routing (single block, one launch) ----------------
__global__ void route_all(const int* __restrict__ sel, const float* __restrict__ scal,
                          int* __restrict__ offsets, int* __restrict__ etok,
                          float* __restrict__ escale) {
  __shared__ int cnt[NEXP], cnt2[NEXP], offs[NEXP+1];
  const int t = threadIdx.x;    // 256 threads, 8 entries each
  if (t < NEXP) { cnt[t] = 0; cnt2[t] = 0; }
  __syncthreads();
  int e8[8];
  #pragma unroll
  for (int q = 0; q < 8; q++) {
    int i = t*8 + q;
    e8[q] = sel[i];
    atomicAdd(&cnt[e8[q]], 1);
  }
  __syncthreads();
  if (t == 0) {
    int s = 0;
    for (int e = 0; e < NEXP; e++) { offs[e] = s; offsets[e] = s; s += cnt[e]; }
    offs[NEXP] = s; offsets[NEXP] = s;
  }
  __syncthreads();
  #pragma unroll
  for (int q = 0; q < 8; q++) {
    int i = t*8 + q;
    int e = e8[q];
    int pos = offs[e] + atomicAdd(&cnt2[e], 1);
    etok[pos]   = i >> 1;       // TOPK == 2
    escale[pos] = scal[i];
  }
}

// ---------------- hidden fp32 -> bf16 (4 MB read, 2 MB write; L2-resident after) ----
__global__ void convert_h(const float* __restrict__ h, bf16_t* __restrict__ hbf) {
  size_t idx = ((size_t)blockIdx.x*256 + threadIdx.x) * 8;
  float4 v0 = ((const float4*)(h + idx))[0];
  float4 v1 = ((const float4*)(h + idx))[1];
  bf16x8 o;
  o[0]=(bf16_t)v0.x; o[1]=(bf16_t)v0.y; o[2]=(bf16_t)v0.z; o[3]=(bf16_t)v0.w;
  o[4]=(bf16_t)v1.x; o[5]=(bf16_t)v1.y; o[6]=(bf16_t)v1.z; o[7]=(bf16_t)v1.w;
  *(bf16x8*)(hbf + idx) = o;
}

// Convert 8 fp32 (2 float4) to a bf16x8 fragment.
__device__ __forceinline__ bf16x8 cvt8(const float4 a, const float4 b) {
  bf16x8 o;
  o[0]=(bf16_t)a.x; o[1]=(bf16_t)a.y; o[2]=(bf16_t)a.z; o[3]=(bf16_t)a.w;
  o[4]=(bf16_t)b.x; o[5]=(bf16_t)b.y; o[6]=(bf16_t)b.z; o[7]=(bf16_t)b.w;
  return o;
}

// ======== LDS-free, barrier-free grouped GEMMs ========
// 16x16x32 MFMA fragments are loaded DIRECTLY from row-major global memory:
//   A frag: lane holds A[m=lr][k=quad*8..+8]  -> one 16B bf16 load from row m
//   B frag: lane holds B[n=lr][k=quad*8..+8]  -> two float4 loads from row n + cvt
// No __shared__, no __syncthreads => compiler pipelines loads across K-iters
// with fine-grained vmcnt (impossible in the 2-barrier LDS structure).
// Block = 256 thr = 4 waves arranged 2(m)x2(n); wave tile 32x32.
// L1/L2 provide cross-wave/cross-block reuse of A rows and B rows.

// GEMM1: act = silu(x@w1g^T + b1g) * (x@w1l^T + b1l)
__global__ __launch_bounds__(256, 4) void gemm1_v4(
    const bf16_t* __restrict__ hbf, const float* __restrict__ w1,
    const float* __restrict__ b1, const int* __restrict__ offsets,
    const int* __restrict__ etok, bf16_t* __restrict__ act)
{
  const int e   = blockIdx.z;
  const int off = offsets[e];
  const int nt  = offsets[e+1] - off;
  const int m0  = blockIdx.y * 64;
  if (m0 >= nt) return;
  const int n0  = blockIdx.x * 64;

  const int tid  = threadIdx.x;
  const int w    = tid >> 6, lane = tid & 63;
  const int quad = lane >> 4, lr = lane & 15;
  const int wm   = w >> 1,  wn = w & 1;

  // A fragment pointers (bf16, 16B per frag)
  const bf16_t* aptr[2];
  #pragma unroll
  for (int i = 0; i < 2; i++) {
    int ent = m0 + wm*32 + i*16 + lr;
    if (ent > nt-1) ent = nt-1;                  // clamp; masked in epilogue
    const int tok = etok[off + ent];
    aptr[i] = hbf + (size_t)tok*HDIM + quad*8;
  }
  // B fragment pointers (fp32 rows of w1; gate and lin)
  const float* gptr[2];
  const float* lptr[2];
  #pragma unroll
  for (int j = 0; j < 2; j++) {
    const int n = n0 + wn*32 + j*16 + lr;
    gptr[j] = w1 + ((size_t)e*2*FDIM + n)*HDIM + quad*8;
    lptr[j] = gptr[j] + (size_t)FDIM*HDIM;
  }

  f32x4 accg[2][2] = {}, accl[2][2] = {};

  for (int k0 = 0; k0 < HDIM; k0 += 32) {
    bf16x8 af[2], gf[2], lf[2];
    #pragma unroll
    for (int i = 0; i < 2; i++)
      af[i] = *(const bf16x8*)(aptr[i] + k0);
    #pragma unroll
    for (int j = 0; j < 2; j++) {
      const float4* gp = (const float4*)(gptr[j] + k0);
      const float4* lp = (const float4*)(lptr[j] + k0);
      float4 ga = gp[0], gb = gp[1];
      float4 la = lp[0], lb = lp[1];
      gf[j] = cvt8(ga, gb);
      lf[j] = cvt8(la, lb);
    }
    #pragma unroll
    for (int i = 0; i < 2; i++)
      #pragma unroll
      for (int j = 0; j < 2; j++) {
        accg[i][j] = __builtin_amdgcn_mfma_f32_16x16x32_bf16(af[i], gf[j], accg[i][j], 0, 0, 0);
        accl[i][j] = __builtin_amdgcn_mfma_f32_16x16x32_bf16(af[i], lf[j], accl[i][j], 0, 0, 0);
      }
  }

  // epilogue: bias + silu(gate)*lin -> act (bf16)
  #pragma unroll
  for (int j = 0; j < 2; j++) {
    const int f = n0 + wn*32 + j*16 + lr;
    const float bg_ = b1[e*2*FDIM + f];
    const float bl_ = b1[e*2*FDIM + FDIM + f];
    #pragma unroll
    for (int i = 0; i < 2; i++) {
      #pragma unroll
      for (int r = 0; r < 4; r++) {
        const int m = wm*32 + i*16 + quad*4 + r;
        if (m0 + m < nt) {
          const float g = accg[i][j][r] + bg_;
          const float l = accl[i][j][r] + bl_;
          const float s = g / (1.f + __expf(-g)) * l;
          act[(size_t)(off + m0 + m)*FDIM + f] = (bf16_t)s;
        }
      }
    }
  }
}

// GEMM2: y = act @ w2^T + b2; out[token] += scale * y  (atomic, split-K x2)
__global__ __launch_bounds__(256, 4) void gemm2_v4(
    const bf16_t* __restrict__ act, const float* __restrict__ w2,
    const float* __restrict__ b2, const int* __restrict__ offsets,
    const int* __restrict__ etok, const float* __restrict__ escale,
    float* __restrict__ out)
{
  const int e   = blockIdx.z;
  const int off = offsets[e];
  const int nt  = offsets[e+1] - off;
  const int m0  = blockIdx.y * 64;
  if (m0 >= nt) return;
  const int n0  = (blockIdx.x >> 1) * 64;
  const int kc  = blockIdx.x & 1;
  const int kbeg = kc * (FDIM/2);

  const int tid  = threadIdx.x;
  const int w    = tid >> 6, lane = tid & 63;
  const int quad = lane >> 4, lr = lane & 15;
  const int wm   = w >> 1,  wn = w & 1;

  const bf16_t* aptr[2];
  #pragma unroll
  for (int i = 0; i < 2; i++) {
    int ent = m0 + wm*32 + i*16 + lr;
    if (ent > nt-1) ent = nt-1;
    aptr[i] = act + (size_t)(off + ent)*FDIM + kbeg + quad*8;
  }
  const float* bptr[2];
  #pragma unroll
  for (int j = 0; j < 2; j++) {
    const int n = n0 + wn*32 + j*16 + lr;
    bptr[j] = w2 + ((size_t)e*HDIM + n)*FDIM + kbeg + quad*8;
  }

  f32x4 acc[2][2] = {};

  for (int k0 = 0; k0 < FDIM/2; k0 += 32) {
    bf16x8 af[2], bfr[2];
    #pragma unroll
    for (int i = 0; i < 2; i++)
      af[i] = *(const bf16x8*)(aptr[i] + k0);
    #pragma unroll
    for (int j = 0; j < 2; j++) {
      const float4* bp = (const float4*)(bptr[j] + k0);
      float4 ba = bp[0], bb = bp[1];
      bfr[j] = cvt8(ba, bb);
    }
    #pragma unroll
    for (int i = 0; i < 2; i++)
      #pragma unroll
      for (int j = 0; j < 2; j++)
        acc[i][j] = __builtin_amdgcn_mfma_f32_16x16x32_bf16(af[i], bfr[j], acc[i][j], 0, 0, 0);
  }

  // epilogue: + b2 (k-chunk 0 only), scale, atomic scatter-add
  #pragma unroll
  for (int i = 0; i < 2; i++) {
    #pragma unroll
    for (int r = 0; r < 4; r++) {
      const int m = wm*32 + i*16 + quad*4 + r;
      if (m0 + m < nt) {
        const int slot = off + m0 + m;
        const int t    = etok[slot];
        const float s  = escale[slot];
        #pragma unroll
        for (int j = 0; j < 2; j++) {
          const int n = n0 + wn*32 + j*16 + lr;
          float v = acc[i][j][r];
          if (kc == 0) v += b2[e*HDIM + n];
          atomicAdd(&out[(size_t)t*HDIM + n], s * v);
        }
      }
    }
  }
}

extern "C" void kernel_launch(void* const* d_in, const int* in_sizes, int n_in,
                              void* d_out, int out_size, void* d_ws, size_t ws_size,
                              hipStream_t stream) {
  const float* hidden = (const float*)d_in[0];
  const int*   sel    = (const int*)d_in[1];
  const float* scal   = (const float*)d_in[2];
  const float* w1     = (const float*)d_in[3];
  const float* b1     = (const float*)d_in[4];
  const float* w2     = (const float*)d_in[5];
  const float* b2     = (const float*)d_in[6];
  float* out = (float*)d_out;

  char* ws = (char*)d_ws;
  int*    offsets = (int*)(ws + WB_OFFSETS);
  int*    etok    = (int*)(ws + WB_ETOK);
  float*  escale  = (float*)(ws + WB_ESCALE);
  bf16_t* act     = (bf16_t*)(ws + WB_ACT);
  bf16_t* hbf     = (bf16_t*)(ws + WB_H);

  hipMemsetAsync(d_out, 0, (size_t)out_size * sizeof(float), stream);

  route_all<<<1, 256, 0, stream>>>(sel, scal, offsets, etok, escale);
  convert_h<<<(int)(H_ELEMS/8/256), 256, 0, stream>>>(hidden, hbf);

  // gemm1: x = n-tile (32), y = m-tile (64 rows; most y early-exit), z = expert.
  gemm1_v4<<<dim3(FDIM/64, NENT/64, NEXP), 256, 0, stream>>>(hbf, w1, b1, offsets, etok, act);
  // gemm2: x = n-tile(16) x splitK(2), y = m-tile, z = expert.
  gemm2_v4<<<dim3((HDIM/64)*2, NENT/64, NEXP), 256, 0, stream>>>(act, w2, b2, offsets, etok, escale, out);
}

// Round 6
// 334.977 us; speedup vs baseline: 1.7160x; 1.7160x over previous
//
#include <hip/hip_runtime.h>
#include <hip/hip_bf16.h>
#include <cstdint>
#include <cstddef>

// Problem constants (fixed by the reference)
#define TDIM 1024
#define HDIM 1024
#define FDIM 2048
#define NEXP 8
#define NENT 2048   // T * K

typedef __bf16 bf16_t;
typedef __bf16 bf16x4 __attribute__((ext_vector_type(4)));
typedef __bf16 bf16x8 __attribute__((ext_vector_type(8)));
typedef float  f32x4  __attribute__((ext_vector_type(4)));

#define H_ELEMS ((size_t)TDIM*HDIM)   // 1048576

// ---------------- workspace layout (bytes) ----------------
#define WB_OFFSETS 0                                   // int[16]
#define WB_ETOK    64
#define WB_ESCALE  (WB_ETOK + NENT*4)
#define WB_ACT     16512                               // bf16[NENT][FDIM] = 8 MB
#define WB_H       (WB_ACT + (size_t)NENT*FDIM*2)      // bf16[T][H] = 2 MB

__device__ __forceinline__ void gload16(const void* g, void* l) {
  __builtin_amdgcn_global_load_lds((const __attribute__((address_space(1))) void*)g,
                                   (__attribute__((address_space(3))) void*)l, 16, 0, 0);
}

__device__ __forceinline__ bf16x8 cvt8(const float4 a, const float4 b) {
  bf16x8 o;
  o[0]=(bf16_t)a.x; o[1]=(bf16_t)a.y; o[2]=(bf16_t)a.z; o[3]=(bf16_t)a.w;
  o[4]=(bf16_t)b.x; o[5]=(bf16_t)b.y; o[6]=(bf16_t)b.z; o[7]=(bf16_t)b.w;
  return o;
}

// ---------------- routing (single block, one launch) ----------------
__global__ void route_all(const int* __restrict__ sel, const float* __restrict__ scal,
                          int* __restrict__ offsets, int* __restrict__ etok,
                          float* __restrict__ escale) {
  __shared__ int cnt[NEXP], cnt2[NEXP], offs[NEXP+1];
  const int t = threadIdx.x;    // 256 threads, 8 entries each
  if (t < NEXP) { cnt[t] = 0; cnt2[t] = 0; }
  __syncthreads();
  int e8[8];
  #pragma unroll
  for (int q = 0; q < 8; q++) {
    int i = t*8 + q;
    e8[q] = sel[i];
    atomicAdd(&cnt[e8[q]], 1);
  }
  __syncthreads();
  if (t == 0) {
    int s = 0;
    for (int e = 0; e < NEXP; e++) { offs[e] = s; offsets[e] = s; s += cnt[e]; }
    offs[NEXP] = s; offsets[NEXP] = s;
  }
  __syncthreads();
  #pragma unroll
  for (int q = 0; q < 8; q++) {
    int i = t*8 + q;
    int e = e8[q];
    int pos = offs[e] + atomicAdd(&cnt2[e], 1);
    etok[pos]   = i >> 1;       // TOPK == 2
    escale[pos] = scal[i];
  }
}

// ---------------- hidden fp32 -> bf16 ----------------
__global__ void convert_h(const float* __restrict__ h, bf16_t* __restrict__ hbf) {
  size_t idx = ((size_t)blockIdx.x*256 + threadIdx.x) * 8;
  float4 v0 = ((const float4*)(h + idx))[0];
  float4 v1 = ((const float4*)(h + idx))[1];
  *(bf16x8*)(hbf + idx) = cvt8(v0, v1);
}

// ======== m97-style grouped GEMMs ========
// Block 256 thr = 4 waves (2m x 2n). BK=32. A (bf16) staged via global_load_lds
// with XOR-seg source swizzle; B (fp32 weights) register-prefetched 1 iter
// ahead, inline-converted, one ds_write_b128 per buffer per thread.
// LDS row = 32 bf16 = 4 segs of 16B; seg s of row r holds global seg s^(r&3).
// Wave tile gemm1: 64m x 32f x{gate,lin} -> 16 MFMA / 8 ds_read_b128.
// Wave tile gemm2: 64m x 64n            -> 16 MFMA / 8 ds_read_b128.

// GEMM1: act = silu(x@w1g^T + b1g) * (x@w1l^T + b1l)
__global__ __launch_bounds__(256, 3) void gemm1_v5(
    const bf16_t* __restrict__ hbf, const float* __restrict__ w1,
    const float* __restrict__ b1, const int* __restrict__ offsets,
    const int* __restrict__ etok, bf16_t* __restrict__ act)
{
  const int e   = blockIdx.z;
  const int off = offsets[e];
  const int nt  = offsets[e+1] - off;
  const int m0  = blockIdx.y * 128;
  if (m0 >= nt) return;
  const int n0  = blockIdx.x * 64;

  __shared__ __align__(16) bf16_t As[128*32];
  __shared__ __align__(16) bf16_t Bg[64*32];
  __shared__ __align__(16) bf16_t Bl[64*32];

  const int tid  = threadIdx.x;
  const int w    = tid >> 6, lane = tid & 63;
  const int quad = lane >> 4, lr = lane & 15;
  const int wm   = w >> 1,  wn = w & 1;

  // ---- A staging: wave w, inst i covers LDS rows [i*64 + w*16, +16) ----
  const bf16_t* asrc[2];
  bf16_t* adst[2];
  #pragma unroll
  for (int i = 0; i < 2; i++) {
    const int row = i*64 + w*16 + (lane >> 2);
    const int seg = (lane & 3) ^ (row & 3);          // source swizzle
    int ent = m0 + row; if (ent > nt-1) ent = nt-1;  // clamp; masked in epilogue
    const int tok = etok[off + ent];
    asrc[i] = hbf + (size_t)tok*HDIM + seg*8;
    adst[i] = &As[(i*64 + w*16)*32];                 // + lane*16B implicit
  }

  // ---- B staging: thread t -> row t>>2 (0..63), seg t&3 ----
  const int br = tid >> 2, bs = tid & 3;
  const float* gsrc = w1 + ((size_t)e*2*FDIM + (size_t)(n0 + br))*HDIM + bs*8;
  const float* lsrc = gsrc + (size_t)FDIM*HDIM;
  const int bofs = br*32 + ((bs ^ (br & 3)) << 3);   // swizzled LDS offset (bf16)

  // ---- loop-invariant fragment LDS offsets ----
  const int aswz = (quad ^ (lr & 3)) << 3;
  int aoff[4], boff[2];
  #pragma unroll
  for (int i = 0; i < 4; i++) aoff[i] = (wm*64 + i*16 + lr)*32 + aswz;
  #pragma unroll
  for (int j = 0; j < 2; j++) boff[j] = (wn*32 + j*16 + lr)*32 + aswz;

  f32x4 accg[4][2] = {}, accl[4][2] = {};

  // prologue: prefetch B(0)
  float4 g4[2], l4[2];
  { const float4* p = (const float4*)gsrc; g4[0]=p[0]; g4[1]=p[1];
    const float4* q = (const float4*)lsrc; l4[0]=q[0]; l4[1]=q[1]; }

  for (int k0 = 0; k0 < HDIM; k0 += 32) {
    __syncthreads();                       // prior iter frag reads done
    gload16(asrc[0] + k0, adst[0]);
    gload16(asrc[1] + k0, adst[1]);
    *(bf16x8*)&Bg[bofs] = cvt8(g4[0], g4[1]);
    *(bf16x8*)&Bl[bofs] = cvt8(l4[0], l4[1]);
    __syncthreads();                       // staging visible (vmcnt drain)

    if (k0 + 32 < HDIM) {                  // prefetch B(k+1); overlaps MFMA phase
      const float4* p = (const float4*)(gsrc + k0 + 32); g4[0]=p[0]; g4[1]=p[1];
      const float4* q = (const float4*)(lsrc + k0 + 32); l4[0]=q[0]; l4[1]=q[1];
    }

    bf16x8 af[4], gf[2], lf[2];
    #pragma unroll
    for (int i = 0; i < 4; i++) af[i] = *(const bf16x8*)&As[aoff[i]];
    #pragma unroll
    for (int j = 0; j < 2; j++) {
      gf[j] = *(const bf16x8*)&Bg[boff[j]];
      lf[j] = *(const bf16x8*)&Bl[boff[j]];
    }
    #pragma unroll
    for (int i = 0; i < 4; i++)
      #pragma unroll
      for (int j = 0; j < 2; j++) {
        accg[i][j] = __builtin_amdgcn_mfma_f32_16x16x32_bf16(af[i], gf[j], accg[i][j], 0, 0, 0);
        accl[i][j] = __builtin_amdgcn_mfma_f32_16x16x32_bf16(af[i], lf[j], accl[i][j], 0, 0, 0);
      }
  }

  // epilogue: bias + silu(gate)*lin -> act (bf16)
  #pragma unroll
  for (int j = 0; j < 2; j++) {
    const int f = n0 + wn*32 + j*16 + lr;
    const float bg_ = b1[e*2*FDIM + f];
    const float bl_ = b1[e*2*FDIM + FDIM + f];
    #pragma unroll
    for (int i = 0; i < 4; i++) {
      #pragma unroll
      for (int r = 0; r < 4; r++) {
        const int m = wm*64 + i*16 + quad*4 + r;
        if (m0 + m < nt) {
          const float g = accg[i][j][r] + bg_;
          const float l = accl[i][j][r] + bl_;
          const float s = g / (1.f + __expf(-g)) * l;
          act[(size_t)(off + m0 + m)*FDIM + f] = (bf16_t)s;
        }
      }
    }
  }
}

// GEMM2: y = act @ w2^T + b2; out[token] += scale * y  (atomic, split-K x4)
__global__ __launch_bounds__(256, 3) void gemm2_v5(
    const bf16_t* __restrict__ act, const float* __restrict__ w2,
    const float* __restrict__ b2, const int* __restrict__ offsets,
    const int* __restrict__ etok, const float* __restrict__ escale,
    float* __restrict__ out)
{
  const int e   = blockIdx.z;
  const int off = offsets[e];
  const int nt  = offsets[e+1] - off;
  const int m0  = blockIdx.y * 128;
  if (m0 >= nt) return;
  const int n0  = (blockIdx.x >> 2) * 128;
  const int kc  = blockIdx.x & 3;
  const int kbeg = kc * (FDIM/4);          // 512-chunk, 16 iters

  __shared__ __align__(16) bf16_t As[128*32];
  __shared__ __align__(16) bf16_t Bs[128*32];

  const int tid  = threadIdx.x;
  const int w    = tid >> 6, lane = tid & 63;
  const int quad = lane >> 4, lr = lane & 15;
  const int wm   = w >> 1,  wn = w & 1;

  const bf16_t* asrc[2];
  bf16_t* adst[2];
  #pragma unroll
  for (int i = 0; i < 2; i++) {
    const int row = i*64 + w*16 + (lane >> 2);
    const int seg = (lane & 3) ^ (row & 3);
    int ent = m0 + row; if (ent > nt-1) ent = nt-1;
    asrc[i] = act + (size_t)(off + ent)*FDIM + kbeg + seg*8;
    adst[i] = &As[(i*64 + w*16)*32];
  }

  // B staging: thread t -> row t>>1 (0..127), col-half t&1 (segs 2c, 2c+1)
  const int br = tid >> 1, bc = tid & 1;
  const float* bsrc = w2 + ((size_t)e*HDIM + (size_t)(n0 + br))*FDIM + kbeg + bc*16;
  const int bofs0 = br*32 + (((2*bc)   ^ (br & 3)) << 3);
  const int bofs1 = br*32 + (((2*bc+1) ^ (br & 3)) << 3);

  const int aswz = (quad ^ (lr & 3)) << 3;
  int aoff[4], boff[4];
  #pragma unroll
  for (int i = 0; i < 4; i++) aoff[i] = (wm*64 + i*16 + lr)*32 + aswz;
  #pragma unroll
  for (int j = 0; j < 4; j++) boff[j] = (wn*64 + j*16 + lr)*32 + aswz;

  f32x4 acc[4][4] = {};

  float4 b4[4];
  { const float4* p = (const float4*)bsrc;
    b4[0]=p[0]; b4[1]=p[1]; b4[2]=p[2]; b4[3]=p[3]; }

  for (int k0 = 0; k0 < FDIM/4; k0 += 32) {
    __syncthreads();
    gload16(asrc[0] + k0, adst[0]);
    gload16(asrc[1] + k0, adst[1]);
    *(bf16x8*)&Bs[bofs0] = cvt8(b4[0], b4[1]);
    *(bf16x8*)&Bs[bofs1] = cvt8(b4[2], b4[3]);
    __syncthreads();

    if (k0 + 32 < FDIM/4) {
      const float4* p = (const float4*)(bsrc + k0 + 32);
      b4[0]=p[0]; b4[1]=p[1]; b4[2]=p[2]; b4[3]=p[3];
    }

    bf16x8 af[4], bfr[4];
    #pragma unroll
    for (int i = 0; i < 4; i++) af[i] = *(const bf16x8*)&As[aoff[i]];
    #pragma unroll
    for (int j = 0; j < 4; j++) bfr[j] = *(const bf16x8*)&Bs[boff[j]];
    #pragma unroll
    for (int i = 0; i < 4; i++)
      #pragma unroll
      for (int j = 0; j < 4; j++)
        acc[i][j] = __builtin_amdgcn_mfma_f32_16x16x32_bf16(af[i], bfr[j], acc[i][j], 0, 0, 0);
  }

  // epilogue: + b2 (k-chunk 0 only), scale, atomic scatter-add
  #pragma unroll
  for (int i = 0; i < 4; i++) {
    #pragma unroll
    for (int r = 0; r < 4; r++) {
      const int m = wm*64 + i*16 + quad*4 + r;
      if (m0 + m < nt) {
        const int slot = off + m0 + m;
        const int t    = etok[slot];
        const float s  = escale[slot];
        #pragma unroll
        for (int j = 0; j < 4; j++) {
          const int n = n0 + wn*64 + j*16 + lr;
          float v = acc[i][j][r];
          if (kc == 0) v += b2[e*HDIM + n];
          atomicAdd(&out[(size_t)t*HDIM + n], s * v);
        }
      }
    }
  }
}

extern "C" void kernel_launch(void* const* d_in, const int* in_sizes, int n_in,
                              void* d_out, int out_size, void* d_ws, size_t ws_size,
                              hipStream_t stream) {
  const float* hidden = (const float*)d_in[0];
  const int*   sel    = (const int*)d_in[1];
  const float* scal   = (const float*)d_in[2];
  const float* w1     = (const float*)d_in[3];
  const float* b1     = (const float*)d_in[4];
  const float* w2     = (const float*)d_in[5];
  const float* b2     = (const float*)d_in[6];
  float* out = (float*)d_out;

  char* ws = (char*)d_ws;
  int*    offsets = (int*)(ws + WB_OFFSETS);
  int*    etok    = (int*)(ws + WB_ETOK);
  float*  escale  = (float*)(ws + WB_ESCALE);
  bf16_t* act     = (bf16_t*)(ws + WB_ACT);
  bf16_t* hbf     = (bf16_t*)(ws + WB_H);

  hipMemsetAsync(d_out, 0, (size_t)out_size * sizeof(float), stream);

  route_all<<<1, 256, 0, stream>>>(sel, scal, offsets, etok, escale);
  convert_h<<<(int)(H_ELEMS/8/256), 256, 0, stream>>>(hidden, hbf);

  // gemm1: x = n-tile (32), y = m-tile (16; ~2 live per expert), z = expert.
  gemm1_v5<<<dim3(FDIM/64, NENT/128, NEXP), 256, 0, stream>>>(hbf, w1, b1, offsets, etok, act);
  // gemm2: x = n-tile(8) x splitK(4), y = m-tile, z = expert. 512 live blocks.
  gemm2_v5<<<dim3((HDIM/128)*4, NENT/128, NEXP), 256, 0, stream>>>(act, w2, b2, offsets, etok, escale, out);
}